// Round 5
// baseline (536.440 us; speedup 1.0000x reference)
//
#include <hip/hip_runtime.h>
#include <hip/hip_bf16.h>

#define RELS 7
#define DIM 64
#define KTOT 512  // 7*64 + 64 (root)

typedef __attribute__((ext_vector_type(8))) short short8;
typedef __attribute__((ext_vector_type(4))) float floatx4;

__device__ inline unsigned short f2b(float f) {
  union { float f; unsigned u; } v; v.f = f;
  unsigned u = v.u + 0x7fffu + ((v.u >> 16) & 1u);  // round-nearest-even
  return (unsigned short)(u >> 16);
}
__device__ inline float b2f(unsigned short b) {
  union { unsigned u; float f; } v; v.u = ((unsigned)b) << 16;
  return v.f;
}

// x f32 -> bf16 (8 elems/thread)
__global__ void __launch_bounds__(256) k_xb(const float* __restrict__ x,
                                            unsigned short* __restrict__ xb, long n8) {
  long t = (long)blockIdx.x * 256 + threadIdx.x;
  if (t >= n8) return;
  const float4* p = reinterpret_cast<const float4*>(x + t * 8);
  float4 f0 = p[0], f1 = p[1];
  short8 o;
  o[0] = (short)f2b(f0.x); o[1] = (short)f2b(f0.y);
  o[2] = (short)f2b(f0.z); o[3] = (short)f2b(f0.w);
  o[4] = (short)f2b(f1.x); o[5] = (short)f2b(f1.y);
  o[6] = (short)f2b(f1.z); o[7] = (short)f2b(f1.w);
  *reinterpret_cast<short8*>(xb + t * 8) = o;
}

// histogram over (dst*8 + rel)
__global__ void __launch_bounds__(256) k_hist(const int* __restrict__ dst,
                                              const int* __restrict__ et,
                                              int* __restrict__ deg, int E) {
  int e = blockIdx.x * 256 + threadIdx.x;
  if (e < E) atomicAdd(&deg[(dst[e] << 3) + et[e]], 1);
}

// block-local exclusive scan over 1024 entries (256 thr x 4)
__global__ void __launch_bounds__(256) k_scan1(const int* __restrict__ deg,
                                               int* __restrict__ start,
                                               int* __restrict__ bsum, int n) {
  __shared__ int sm[256];
  int t = threadIdx.x;
  int base = blockIdx.x * 1024 + t * 4;
  int v0 = (base + 0 < n) ? deg[base + 0] : 0;
  int v1 = (base + 1 < n) ? deg[base + 1] : 0;
  int v2 = (base + 2 < n) ? deg[base + 2] : 0;
  int v3 = (base + 3 < n) ? deg[base + 3] : 0;
  int s = v0 + v1 + v2 + v3;
  sm[t] = s;
  __syncthreads();
  for (int off = 1; off < 256; off <<= 1) {
    int a = (t >= off) ? sm[t - off] : 0;
    __syncthreads();
    sm[t] += a;
    __syncthreads();
  }
  int excl = sm[t] - s;
  if (base + 0 < n) start[base + 0] = excl;
  excl += v0;
  if (base + 1 < n) start[base + 1] = excl;
  excl += v1;
  if (base + 2 < n) start[base + 2] = excl;
  excl += v2;
  if (base + 3 < n) start[base + 3] = excl;
  if (t == 255) bsum[blockIdx.x] = sm[255];
}

// single-block exclusive scan over up to 1024 block sums (in place)
__global__ void __launch_bounds__(256) k_scan2(int* bsum, int nb) {
  __shared__ int sm[256];
  int t = threadIdx.x;
  int base = t * 4;
  int v0 = (base + 0 < nb) ? bsum[base + 0] : 0;
  int v1 = (base + 1 < nb) ? bsum[base + 1] : 0;
  int v2 = (base + 2 < nb) ? bsum[base + 2] : 0;
  int v3 = (base + 3 < nb) ? bsum[base + 3] : 0;
  int s = v0 + v1 + v2 + v3;
  sm[t] = s;
  __syncthreads();
  for (int off = 1; off < 256; off <<= 1) {
    int a = (t >= off) ? sm[t - off] : 0;
    __syncthreads();
    sm[t] += a;
    __syncthreads();
  }
  int excl = sm[t] - s;
  if (base + 0 < nb) bsum[base + 0] = excl;
  excl += v0;
  if (base + 1 < nb) bsum[base + 1] = excl;
  excl += v1;
  if (base + 2 < nb) bsum[base + 2] = excl;
  excl += v2;
  if (base + 3 < nb) bsum[base + 3] = excl;
}

__global__ void __launch_bounds__(256) k_scan3(int* __restrict__ start,
                                               int* __restrict__ cursor,
                                               const int* __restrict__ bsum,
                                               int n, int E) {
  int i = blockIdx.x * 256 + threadIdx.x;
  if (i < n) {
    int v = start[i] + bsum[i >> 10];
    start[i] = v;
    cursor[i] = v;
  } else if (i == n) {
    start[n] = E;
  }
}

// esrc word: src | rel<<17 | (dst&15)<<20   (src < 2^17, rel < 7, 16-node chunk)
__global__ void __launch_bounds__(256) k_bucket(const int* __restrict__ ei,
                                                const int* __restrict__ et,
                                                int* __restrict__ cursor,
                                                int* __restrict__ esrc, int E) {
  int e = blockIdx.x * 256 + threadIdx.x;
  if (e >= E) return;
  int s = ei[e], d = ei[E + e], r = et[e];
  int pos = atomicAdd(&cursor[(d << 3) + r], 1);
  esrc[pos] = s | (r << 17) | ((d & 15) << 20);
}

// edge-parallel aggregation: block = 16 dst nodes, LDS f32 acc, ds_add_f32
__global__ void __launch_bounds__(256) k_seg2(const int* __restrict__ start,
                                              const int* __restrict__ esrc,
                                              const unsigned short* __restrict__ xb,
                                              unsigned short* __restrict__ mn,
                                              int N, int NS) {
  __shared__ float acc[16 * 8 * 64];  // [local][rel(8, pad)][ch] = 32 KiB
  const int tid = threadIdx.x;
  const int lane = tid & 63;
  const int wv = tid >> 6;
  const int b = blockIdx.x;

  for (int i = tid; i < 16 * 8 * 64; i += 256) acc[i] = 0.0f;
  __syncthreads();

  const int segbase = b << 7;  // 16 nodes * 8 segments
  const int a0 = start[segbase];
  int hi = segbase + 128; if (hi > NS) hi = NS;
  const int end = start[hi];

  for (int e = a0 + (wv << 2); e < end; e += 16) {
    int i1 = (e + 1 < end) ? e + 1 : e;
    int i2 = (e + 2 < end) ? e + 2 : e;
    int i3 = (e + 3 < end) ? e + 3 : e;
    int v0 = esrc[e], v1 = esrc[i1], v2 = esrc[i2], v3 = esrc[i3];
    float f0 = b2f(xb[((long)(v0 & 0x1FFFF) << 6) + lane]);
    float f1 = b2f(xb[((long)(v1 & 0x1FFFF) << 6) + lane]);
    float f2 = b2f(xb[((long)(v2 & 0x1FFFF) << 6) + lane]);
    float f3 = b2f(xb[((long)(v3 & 0x1FFFF) << 6) + lane]);
    atomicAdd(&acc[(((v0 >> 17) & 127) << 6) + lane], f0);
    if (e + 1 < end) atomicAdd(&acc[(((v1 >> 17) & 127) << 6) + lane], f1);
    if (e + 2 < end) atomicAdd(&acc[(((v2 >> 17) & 127) << 6) + lane], f2);
    if (e + 3 < end) atomicAdd(&acc[(((v3 >> 17) & 127) << 6) + lane], f3);
  }
  __syncthreads();

  // means: one (node, rel) per wave-step; count = segment length (free)
  int nloc = N - (b << 4); if (nloc > 16) nloc = 16;
  for (int q = wv; q < nloc * RELS; q += 4) {
    int node = q / RELS;
    int r = q - node * RELS;
    int g = (b << 4) + node;
    int s0 = start[(g << 3) + r];
    int s1 = start[(g << 3) + r + 1];
    float inv = __builtin_amdgcn_rcpf(fmaxf((float)(s1 - s0), 1.0f));
    float v = acc[(((node << 3) + r) << 6) + lane];
    mn[((long)g * RELS + r) * DIM + lane] = f2b(v * inv);
  }
}

// out[i][:] = [mn[i] | xb[i]] (K=512, bf16) @ [W;root] + bias
__global__ void __launch_bounds__(256) k_gemm(const unsigned short* __restrict__ mn,
                                              const unsigned short* __restrict__ xb,
                                              const float* __restrict__ W,
                                              const float* __restrict__ root,
                                              const float* __restrict__ bias,
                                              float* __restrict__ out, int N)
{
  __shared__ short Bl[KTOT * DIM];  // 64 KiB, MFMA-fragment order
  const int tid = threadIdx.x;

  for (int g = tid; g < 4096; g += 256) {
    int kb = g >> 6, col = g & 63;
    short8 tmp;
#pragma unroll
    for (int j = 0; j < 8; ++j) {
      int k = kb * 8 + j;
      float w = (k < 448) ? W[k * 64 + col] : root[(k - 448) * 64 + col];
      tmp[j] = (short)f2b(w);
    }
    *reinterpret_cast<short8*>(&Bl[g * 8]) = tmp;
  }
  __syncthreads();

  const int lane = tid & 63;
  const int wv = tid >> 6;
  const int rowbase = blockIdx.x * 64 + wv * 16;
  const int row16 = lane & 15;
  const int kg = lane >> 4;
  int i = rowbase + row16;
  if (i > N - 1) i = N - 1;

  floatx4 c0 = {0,0,0,0}, c1 = {0,0,0,0}, c2 = {0,0,0,0}, c3 = {0,0,0,0};
  const short8* Bv = reinterpret_cast<const short8*>(Bl);

#pragma unroll
  for (int kk = 0; kk < 16; ++kk) {
    const int r = kk >> 1;
    const int d0 = (kk * 32 + kg * 8) & 63;
    const unsigned short* ap = (r < RELS)
        ? (mn + (long)i * (RELS * DIM) + r * DIM + d0)
        : (xb + (long)i * DIM + d0);
    short8 aa = *reinterpret_cast<const short8*>(ap);
    const int bb = (kk * 4 + kg) * 64 + row16;
    c0 = __builtin_amdgcn_mfma_f32_16x16x32_bf16(aa, Bv[bb],      c0, 0, 0, 0);
    c1 = __builtin_amdgcn_mfma_f32_16x16x32_bf16(aa, Bv[bb + 16], c1, 0, 0, 0);
    c2 = __builtin_amdgcn_mfma_f32_16x16x32_bf16(aa, Bv[bb + 32], c2, 0, 0, 0);
    c3 = __builtin_amdgcn_mfma_f32_16x16x32_bf16(aa, Bv[bb + 48], c3, 0, 0, 0);
  }

  const int rowoff = kg * 4;
#pragma unroll
  for (int t = 0; t < 4; ++t) {
    floatx4 c = (t == 0) ? c0 : (t == 1) ? c1 : (t == 2) ? c2 : c3;
    const int col = t * 16 + row16;
    const float b = bias[col];
#pragma unroll
    for (int q = 0; q < 4; ++q) {
      int row = rowbase + rowoff + q;
      if (row < N) out[(long)row * DIM + col] = c[q] + b;
    }
  }
}

extern "C" void kernel_launch(void* const* d_in, const int* in_sizes, int n_in,
                              void* d_out, int out_size, void* d_ws, size_t ws_size,
                              hipStream_t stream)
{
  const float* x    = (const float*)d_in[0];
  const float* W    = (const float*)d_in[1];
  const float* root = (const float*)d_in[2];
  const float* bias = (const float*)d_in[3];
  const int*   ei   = (const int*)d_in[4];
  const int*   et   = (const int*)d_in[5];
  float* out = (float*)d_out;

  const int N = in_sizes[0] / DIM;
  const int E = in_sizes[4] / 2;
  const int NS = N * 8;  // segments = dst*8 + rel (r=7 bucket always empty)

  // workspace layout
  unsigned short* mn = (unsigned short*)d_ws;            // [N][7][64] bf16
  unsigned short* xb = mn + (size_t)N * RELS * DIM;      // [N][64] bf16
  int* esrc   = (int*)(xb + (size_t)N * DIM);            // [E]
  int* deg    = esrc + E;                                // [NS]
  int* start  = deg + NS;                                // [NS+1]
  int* cursor = start + NS + 1;                          // [NS]
  int* bsum   = cursor + NS;                             // [ceil(NS/1024)]

  hipMemsetAsync(deg, 0, (size_t)NS * sizeof(int), stream);
  k_xb<<<(int)(((long)N * DIM / 8 + 255) / 256), 256, 0, stream>>>(x, xb, (long)N * DIM / 8);
  k_hist<<<(E + 255) / 256, 256, 0, stream>>>(ei + E, et, deg, E);
  int nb = (NS + 1023) / 1024;
  k_scan1<<<nb, 256, 0, stream>>>(deg, start, bsum, NS);
  k_scan2<<<1, 256, 0, stream>>>(bsum, nb);
  k_scan3<<<(NS + 1 + 255) / 256, 256, 0, stream>>>(start, cursor, bsum, NS, E);
  k_bucket<<<(E + 255) / 256, 256, 0, stream>>>(ei, et, cursor, esrc, E);
  k_seg2<<<(N + 15) / 16, 256, 0, stream>>>(start, esrc, xb, mn, N, NS);
  k_gemm<<<(N + 63) / 64, 256, 0, stream>>>(mn, xb, W, root, bias, out, N);
}

// Round 6
// 260.821 us; speedup vs baseline: 2.0567x; 2.0567x over previous
//
#include <hip/hip_runtime.h>
#include <hip/hip_bf16.h>

#define RELS 7
#define DIM 64
#define KTOT 512  // 7*64 + 64 (root)

typedef __attribute__((ext_vector_type(8))) short short8;
typedef __attribute__((ext_vector_type(4))) float floatx4;

__device__ inline unsigned short f2b(float f) {
  union { float f; unsigned u; } v; v.f = f;
  unsigned u = v.u + 0x7fffu + ((v.u >> 16) & 1u);  // round-nearest-even
  return (unsigned short)(u >> 16);
}
__device__ inline float b2f(unsigned short b) {
  union { unsigned u; float f; } v; v.u = ((unsigned)b) << 16;
  return v.f;
}

// x f32 -> bf16 (8 elems/thread)
__global__ void __launch_bounds__(256) k_xb(const float* __restrict__ x,
                                            unsigned short* __restrict__ xb, long n8) {
  long t = (long)blockIdx.x * 256 + threadIdx.x;
  if (t >= n8) return;
  const float4* p = reinterpret_cast<const float4*>(x + t * 8);
  float4 f0 = p[0], f1 = p[1];
  short8 o;
  o[0] = (short)f2b(f0.x); o[1] = (short)f2b(f0.y);
  o[2] = (short)f2b(f0.z); o[3] = (short)f2b(f0.w);
  o[4] = (short)f2b(f1.x); o[5] = (short)f2b(f1.y);
  o[6] = (short)f2b(f1.z); o[7] = (short)f2b(f1.w);
  *reinterpret_cast<short8*>(xb + t * 8) = o;
}

// [W;root] f32 -> bf16 in MFMA-fragment order (one-time, 64 KiB)
__global__ void __launch_bounds__(256) k_wb(const float* __restrict__ W,
                                            const float* __restrict__ root,
                                            unsigned short* __restrict__ Blg) {
  int g = blockIdx.x * 256 + threadIdx.x;  // 4096 groups
  if (g >= 4096) return;
  int kb = g >> 6, col = g & 63;
  short8 tmp;
#pragma unroll
  for (int j = 0; j < 8; ++j) {
    int k = kb * 8 + j;
    float w = (k < 448) ? W[k * 64 + col] : root[(k - 448) * 64 + col];
    tmp[j] = (short)f2b(w);
  }
  *reinterpret_cast<short8*>(&Blg[g * 8]) = tmp;
}

// histogram over (dst*8 + rel)
__global__ void __launch_bounds__(256) k_hist(const int* __restrict__ dst,
                                              const int* __restrict__ et,
                                              int* __restrict__ deg, int E) {
  int e = blockIdx.x * 256 + threadIdx.x;
  if (e < E) atomicAdd(&deg[(dst[e] << 3) + et[e]], 1);
}

// block-local exclusive scan over 1024 entries (256 thr x 4)
__global__ void __launch_bounds__(256) k_scan1(const int* __restrict__ deg,
                                               int* __restrict__ start,
                                               int* __restrict__ bsum, int n) {
  __shared__ int sm[256];
  int t = threadIdx.x;
  int base = blockIdx.x * 1024 + t * 4;
  int v0 = (base + 0 < n) ? deg[base + 0] : 0;
  int v1 = (base + 1 < n) ? deg[base + 1] : 0;
  int v2 = (base + 2 < n) ? deg[base + 2] : 0;
  int v3 = (base + 3 < n) ? deg[base + 3] : 0;
  int s = v0 + v1 + v2 + v3;
  sm[t] = s;
  __syncthreads();
  for (int off = 1; off < 256; off <<= 1) {
    int a = (t >= off) ? sm[t - off] : 0;
    __syncthreads();
    sm[t] += a;
    __syncthreads();
  }
  int excl = sm[t] - s;
  if (base + 0 < n) start[base + 0] = excl;
  excl += v0;
  if (base + 1 < n) start[base + 1] = excl;
  excl += v1;
  if (base + 2 < n) start[base + 2] = excl;
  excl += v2;
  if (base + 3 < n) start[base + 3] = excl;
  if (t == 255) bsum[blockIdx.x] = sm[255];
}

// single-block exclusive scan over up to 1024 block sums (in place)
__global__ void __launch_bounds__(256) k_scan2(int* bsum, int nb) {
  __shared__ int sm[256];
  int t = threadIdx.x;
  int base = t * 4;
  int v0 = (base + 0 < nb) ? bsum[base + 0] : 0;
  int v1 = (base + 1 < nb) ? bsum[base + 1] : 0;
  int v2 = (base + 2 < nb) ? bsum[base + 2] : 0;
  int v3 = (base + 3 < nb) ? bsum[base + 3] : 0;
  int s = v0 + v1 + v2 + v3;
  sm[t] = s;
  __syncthreads();
  for (int off = 1; off < 256; off <<= 1) {
    int a = (t >= off) ? sm[t - off] : 0;
    __syncthreads();
    sm[t] += a;
    __syncthreads();
  }
  int excl = sm[t] - s;
  if (base + 0 < nb) bsum[base + 0] = excl;
  excl += v0;
  if (base + 1 < nb) bsum[base + 1] = excl;
  excl += v1;
  if (base + 2 < nb) bsum[base + 2] = excl;
  excl += v2;
  if (base + 3 < nb) bsum[base + 3] = excl;
}

__global__ void __launch_bounds__(256) k_scan3(int* __restrict__ start,
                                               int* __restrict__ cursor,
                                               const int* __restrict__ bsum,
                                               int n, int E) {
  int i = blockIdx.x * 256 + threadIdx.x;
  if (i < n) {
    int v = start[i] + bsum[i >> 10];
    start[i] = v;
    cursor[i] = v;
  } else if (i == n) {
    start[n] = E;
  }
}

// esrc word: src | rel<<17   (src < 2^17, rel < 7)
__global__ void __launch_bounds__(256) k_bucket(const int* __restrict__ ei,
                                                const int* __restrict__ et,
                                                int* __restrict__ cursor,
                                                int* __restrict__ esrc, int E) {
  int e = blockIdx.x * 256 + threadIdx.x;
  if (e >= E) return;
  int s = ei[e], d = ei[E + e], r = et[e];
  int pos = atomicAdd(&cursor[(d << 3) + r], 1);
  esrc[pos] = s | (r << 17);
}

// one wave per dst node; node's edges contiguous & rel-sorted.
// Coalesced edge-word load, 8-deep independent gathers, uniform-branch routing.
__global__ void __launch_bounds__(256) k_seg(const int* __restrict__ start,
                                             const int* __restrict__ esrc,
                                             const unsigned short* __restrict__ xb,
                                             unsigned short* __restrict__ mn, int N) {
  int node = (int)(((long)blockIdx.x * 256 + threadIdx.x) >> 6);
  int lane = threadIdx.x & 63;
  if (node >= N) return;
  int sv = 0;
  if (lane < 8) sv = start[(node << 3) + lane];  // boundaries r=0..7
  const int a0 = __shfl(sv, 0, 64);
  const int aE = __shfl(sv, 7, 64);

  float acc0 = 0, acc1 = 0, acc2 = 0, acc3 = 0, acc4 = 0, acc5 = 0, acc6 = 0;

  for (int base = a0; base < aE; base += 64) {
    int idx = base + lane;
    int ew = (idx < aE) ? esrc[idx] : 0;   // one coalesced load for 64 edges
    int m = aE - base; if (m > 64) m = 64;
    for (int j0 = 0; j0 < m; j0 += 8) {
      int jm = m - j0; if (jm > 8) jm = 8;
      float g[8]; int rl[8];
#pragma unroll
      for (int j = 0; j < 8; ++j) {
        if (j < jm) {
          int w = __shfl(ew, j0 + j, 64);
          g[j] = b2f(xb[((long)(w & 0x1FFFF) << 6) + lane]);
          rl[j] = (w >> 17) & 7;
        }
      }
#pragma unroll
      for (int j = 0; j < 8; ++j) {
        if (j < jm) {
          int r = __builtin_amdgcn_readfirstlane(rl[j]);  // wave-uniform
          switch (r) {
            case 0: acc0 += g[j]; break;
            case 1: acc1 += g[j]; break;
            case 2: acc2 += g[j]; break;
            case 3: acc3 += g[j]; break;
            case 4: acc4 += g[j]; break;
            case 5: acc5 += g[j]; break;
            default: acc6 += g[j]; break;
          }
        }
      }
    }
  }

  // means: count = boundary diff (free)
  long o = (long)node * (RELS * DIM) + lane;
#pragma unroll
  for (int r = 0; r < RELS; ++r) {
    int s0 = __shfl(sv, r, 64);
    int s1 = __shfl(sv, r + 1, 64);
    float a = (r == 0) ? acc0 : (r == 1) ? acc1 : (r == 2) ? acc2 :
              (r == 3) ? acc3 : (r == 4) ? acc4 : (r == 5) ? acc5 : acc6;
    float inv = __builtin_amdgcn_rcpf(fmaxf((float)(s1 - s0), 1.0f));
    mn[o + (long)r * DIM] = f2b(a * inv);
  }
}

// out[i][:] = [mn[i] | xb[i]] (K=512, bf16) @ Blg + bias
__global__ void __launch_bounds__(256) k_gemm(const unsigned short* __restrict__ mn,
                                              const unsigned short* __restrict__ xb,
                                              const unsigned short* __restrict__ Blg,
                                              const float* __restrict__ bias,
                                              float* __restrict__ out, int N)
{
  __shared__ short Bl[KTOT * DIM];  // 64 KiB, MFMA-fragment order
  const int tid = threadIdx.x;

  {
    const short8* src = reinterpret_cast<const short8*>(Blg);
    short8* dst = reinterpret_cast<short8*>(Bl);
#pragma unroll
    for (int i = 0; i < 16; ++i) dst[tid + i * 256] = src[tid + i * 256];
  }
  __syncthreads();

  const int lane = tid & 63;
  const int wv = tid >> 6;
  const int rowbase = blockIdx.x * 64 + wv * 16;
  const int row16 = lane & 15;
  const int kg = lane >> 4;
  int i = rowbase + row16;
  if (i > N - 1) i = N - 1;

  floatx4 c0 = {0,0,0,0}, c1 = {0,0,0,0}, c2 = {0,0,0,0}, c3 = {0,0,0,0};
  const short8* Bv = reinterpret_cast<const short8*>(Bl);

#pragma unroll
  for (int kk = 0; kk < 16; ++kk) {
    const int r = kk >> 1;
    const int d0 = (kk * 32 + kg * 8) & 63;
    const unsigned short* ap = (r < RELS)
        ? (mn + (long)i * (RELS * DIM) + r * DIM + d0)
        : (xb + (long)i * DIM + d0);
    short8 aa = *reinterpret_cast<const short8*>(ap);
    const int bb = (kk * 4 + kg) * 64 + row16;
    c0 = __builtin_amdgcn_mfma_f32_16x16x32_bf16(aa, Bv[bb],      c0, 0, 0, 0);
    c1 = __builtin_amdgcn_mfma_f32_16x16x32_bf16(aa, Bv[bb + 16], c1, 0, 0, 0);
    c2 = __builtin_amdgcn_mfma_f32_16x16x32_bf16(aa, Bv[bb + 32], c2, 0, 0, 0);
    c3 = __builtin_amdgcn_mfma_f32_16x16x32_bf16(aa, Bv[bb + 48], c3, 0, 0, 0);
  }

  const int rowoff = kg * 4;
#pragma unroll
  for (int t = 0; t < 4; ++t) {
    floatx4 c = (t == 0) ? c0 : (t == 1) ? c1 : (t == 2) ? c2 : c3;
    const int col = t * 16 + row16;
    const float b = bias[col];
#pragma unroll
    for (int q = 0; q < 4; ++q) {
      int row = rowbase + rowoff + q;
      if (row < N) out[(long)row * DIM + col] = c[q] + b;
    }
  }
}

extern "C" void kernel_launch(void* const* d_in, const int* in_sizes, int n_in,
                              void* d_out, int out_size, void* d_ws, size_t ws_size,
                              hipStream_t stream)
{
  const float* x    = (const float*)d_in[0];
  const float* W    = (const float*)d_in[1];
  const float* root = (const float*)d_in[2];
  const float* bias = (const float*)d_in[3];
  const int*   ei   = (const int*)d_in[4];
  const int*   et   = (const int*)d_in[5];
  float* out = (float*)d_out;

  const int N = in_sizes[0] / DIM;
  const int E = in_sizes[4] / 2;
  const int NS = N * 8;  // segments = dst*8 + rel (r=7 bucket always empty)

  // workspace layout
  unsigned short* mn = (unsigned short*)d_ws;            // [N][7][64] bf16
  unsigned short* xb = mn + (size_t)N * RELS * DIM;      // [N][64] bf16
  unsigned short* Blg = xb + (size_t)N * DIM;            // [4096*8] bf16 (64 KiB)
  int* esrc   = (int*)(Blg + 4096 * 8);                  // [E]
  int* deg    = esrc + E;                                // [NS]
  int* start  = deg + NS;                                // [NS+1]
  int* cursor = start + NS + 1;                          // [NS]
  int* bsum   = cursor + NS;                             // [ceil(NS/1024)]

  hipMemsetAsync(deg, 0, (size_t)NS * sizeof(int), stream);
  k_xb<<<(int)(((long)N * DIM / 8 + 255) / 256), 256, 0, stream>>>(x, xb, (long)N * DIM / 8);
  k_wb<<<16, 256, 0, stream>>>(W, root, Blg);
  k_hist<<<(E + 255) / 256, 256, 0, stream>>>(ei + E, et, deg, E);
  int nb = (NS + 1023) / 1024;
  k_scan1<<<nb, 256, 0, stream>>>(deg, start, bsum, NS);
  k_scan2<<<1, 256, 0, stream>>>(bsum, nb);
  k_scan3<<<(NS + 1 + 255) / 256, 256, 0, stream>>>(start, cursor, bsum, NS, E);
  k_bucket<<<(E + 255) / 256, 256, 0, stream>>>(ei, et, cursor, esrc, E);
  k_seg<<<(N + 3) / 4, 256, 0, stream>>>(start, esrc, xb, mn, N);
  k_gemm<<<(N + 63) / 64, 256, 0, stream>>>(mn, xb, Blg, bias, out, N);
}